// Round 1
// baseline (12281.274 us; speedup 1.0000x reference)
//
#include <hip/hip_runtime.h>
#include <hip/hip_fp16.h>
#include <math.h>

#define N_T 16384
#define S   128
#define S3  384
#define THREADS 512          // 8 waves, 2 per SIMD
#define CHUNK 16             // gi steps staged per LDS chunk

// raw barrier: LDS-visibility only (NO vmcnt drain -> in-flight global loads
// can cross barriers freely, unlike __syncthreads()).
#define BAR() do { \
    asm volatile("s_waitcnt lgkmcnt(0)" ::: "memory"); \
    __builtin_amdgcn_s_barrier();                      \
    asm volatile("" ::: "memory");                     \
} while (0)

// ---------------------------------------------------------------------------
// Kernel 0: fold proj into w_ih (fp32).
//   M[j][m]  = sum_{k<127} w_ih[j][k] * proj_w[k][m]        (384 x 128)
//   b2[j]    = b_ih[j] + sum_{k<127} w_ih[j][k] * proj_b[k]
//   mc[j]    = w_ih[j][127]   (mask column coeff, added only at t==0)
// ---------------------------------------------------------------------------
__global__ void prep_kernel(const float* __restrict__ w_ih,
                            const float* __restrict__ b_ih,
                            const float* __restrict__ proj_w,
                            const float* __restrict__ proj_b,
                            float* __restrict__ Mt,
                            float* __restrict__ b2,
                            float* __restrict__ mc) {
    int j = blockIdx.x;    // 0..383
    int m = threadIdx.x;   // 0..127
    float acc = 0.f;
    for (int k = 0; k < S - 1; ++k)
        acc += w_ih[j * S + k] * proj_w[k * S + m];
    Mt[m * S3 + j] = acc;
    if (m == 0) {
        float a = 0.f;
        for (int k = 0; k < S - 1; ++k) a += w_ih[j * S + k] * proj_b[k];
        b2[j] = b_ih[j] + a;
        mc[j] = w_ih[j * S + (S - 1)];
    }
}

// ---------------------------------------------------------------------------
// Kernel 0b: convert w_hh to packed f16 pairs, k-split pairing:
// Whh16[j*64 + m] packs (w_hh[j][m], w_hh[j][m+64]) as half2 in one uint.
// This matches the in-register h pack (h[i], h[i+64]) built per step.
// ---------------------------------------------------------------------------
__global__ void wcvt_kernel(const float* __restrict__ w_hh,
                            unsigned* __restrict__ Whh16) {
    int j = blockIdx.x;    // row 0..383
    int m = threadIdx.x;   // word 0..63
    __half2 p = __floats2half2_rn(w_hh[j * S + m], w_hh[j * S + m + 64]);
    Whh16[j * 64 + m] = *(unsigned*)&p;
}

// ---------------------------------------------------------------------------
// Kernel 1: gi[t][j] = b2[j] + dot(evs[t], M[j]) + (t==0 ? mc[j] : 0)  (fp32)
// ---------------------------------------------------------------------------
#define TB 32
__global__ void gi_kernel(const float* __restrict__ evs,
                          const float* __restrict__ Mt,
                          const float* __restrict__ b2,
                          const float* __restrict__ mc,
                          float* __restrict__ gi) {
    int j  = threadIdx.x;        // 0..383
    int t0 = blockIdx.x * TB;

    float mcol[S];
#pragma unroll
    for (int k = 0; k < S; ++k) mcol[k] = Mt[k * S3 + j];

    __shared__ float ev[TB][S];
    for (int i = j; i < TB * S; i += S3)
        ev[i / S][i % S] = evs[t0 * S + i];
    __syncthreads();

    float bb  = b2[j];
    float mcj = mc[j];
    for (int tt = 0; tt < TB; ++tt) {
        int t = t0 + tt;
        float acc = bb + ((t == 0) ? mcj : 0.f);
#pragma unroll
        for (int k = 0; k < S; ++k) acc += ev[tt][k] * mcol[k];
        gi[t * S3 + j] = acc;
    }
}

// ---------------------------------------------------------------------------
// Kernel 2: sequential GRU scan. 1 workgroup, 512 threads = 8 waves (2/SIMD).
//
// ONE barrier per step; h never round-trips through LDS.
//   wave (g = wv>>2 in {0,1}, c = wv&3): rows {192g+l, +64, +128}, words
//   [16c,16c+16) of the (h[i],h[i+64]) packing. 48 dot2/lane, weights in
//   VGPRs (48 words/lane).
//   Partials -> partT[t&1], XOR-salted: dword 4*row + (c ^ ((row>>3)&3)).
//   Writes are conflict-free b32; gate reads one aligned ds_read_b128 per
//   gate row (the 4 chunk values arrive permuted -> summed, order free).
//   BAR. Gate: every lane computes ONE output row R = 16c+(l&15)+64*(l>=16)
//   (3x redundant across g-groups, 2x mirrored in-wave), then rebuilds the
//   broadcast word p = (h16[R], h16[R+64]) via ds_swizzle xor16 + pack.
//   Next step's matvec readlanes p directly -> no second barrier.
//   gi gate operands are prefetched from LDS at step top (hidden under
//   matvec); gi chunk loads issue at tc==0, LDS-write at tc==14 (14 steps
//   of global-load flight; raw barriers never drain vmcnt).
// ---------------------------------------------------------------------------
__global__ __attribute__((amdgpu_flat_work_group_size(THREADS, THREADS),
                          amdgpu_waves_per_eu(2, 2))) void
scan_kernel(const float* __restrict__ gi,
            const unsigned* __restrict__ Whh16,
            const float* __restrict__ h0,
            const float* __restrict__ b_hh,
            const float* __restrict__ final_w,
            const float* __restrict__ final_b,
            float* __restrict__ out) {
    const int tid = threadIdx.x;
    const int l   = tid & 63;
    const int wv  = tid >> 6;        // 0..7
    const int g   = wv >> 2;         // row-half 0..1
    const int c   = wv & 3;          // k-chunk (wave-uniform)
    const int ra  = 192 * g + l;     // matvec rows ra, ra+64, ra+128
    const int rb  = ra + 64;
    const int rc  = ra + 128;

    // gate row owned by this lane (lanes 32..63 mirror 0..31)
    const int R  = (c << 4) + (l & 15) + ((l & 16) << 2);
    const int cs = c ^ ((l >> 3) & 3);          // partial-write XOR salt

    // packed f16 weight pairs, word i = (w[r][16c+i], w[r][16c+i+64])
    unsigned wa[16], wb[16], wc[16];
    {
        const unsigned* pa = Whh16 + (size_t)ra * 64 + (c << 4);
#pragma unroll
        for (int i = 0; i < 16; ++i) {
            wa[i] = pa[i];
            wb[i] = pa[i + 64 * 64];
            wc[i] = pa[i + 128 * 64];
        }
    }

    __shared__ __align__(16) float gib[2][CHUNK][S3];   // gi double buffer
    __shared__ __align__(16) float partT[2][S3 * 4];    // salted partials
    __shared__ float hfin[S];

    // gate constants + initial h and broadcast pack
    float br = b_hh[R];
    float bz = b_hh[R + S];
    float bn = b_hh[R + 2 * S];
    float hreg = h0[R];
    unsigned p;
    {
        unsigned hu = (unsigned)__half_as_ushort(__float2half(hreg));
        unsigned ou = (unsigned)__builtin_amdgcn_ds_swizzle((int)hu, 0x401F);
        p = hu | (ou << 16);         // lanes 0..15: (h[R], h[R+64])
    }

    // prologue: stage chunk 0 (1536 float4 / 512 thr = 3 each)
    {
        const float4* src = (const float4*)gi;
        float4* dst = (float4*)(&gib[0][0][0]);
        dst[tid]           = src[tid];
        dst[tid + 512]     = src[tid + 512];
        dst[tid + 1024]    = src[tid + 1024];
    }
    BAR();

    float4 st0 = make_float4(0.f, 0.f, 0.f, 0.f);
    float4 st1 = st0, st2 = st0;

    for (int t = 0; t < N_T; ++t) {
        const int tc  = t & (CHUNK - 1);
        const int par = (t >> 4) & 1;
        const int buf = t & 1;

        // issue next-chunk global loads at chunk start (held in regs)
        if (tc == 0 && t + CHUNK < N_T) {
            const float4* src = (const float4*)(gi + (size_t)(t + CHUNK) * S3);
            st0 = src[tid];
            st1 = src[tid + 512];
            st2 = src[tid + 1024];
        }

        // prefetch this step's gi gate operands (buffer stable all chunk)
        float gr = gib[par][tc][R];
        float gz = gib[par][tc][R + S];
        float gn = gib[par][tc][R + 2 * S];

        // matvec: 16 readlane + 48 dot2, h broadcast through SGPRs
        float a0 = 0.f, a1 = 0.f, a2 = 0.f;
#pragma unroll
        for (int i = 0; i < 16; ++i) {
            int hs = __builtin_amdgcn_readlane((int)p, i);
            asm("v_dot2_f32_f16 %0, %2, %1, %0" : "+v"(a0) : "v"(wa[i]), "s"(hs));
            asm("v_dot2_f32_f16 %0, %2, %1, %0" : "+v"(a1) : "v"(wb[i]), "s"(hs));
            asm("v_dot2_f32_f16 %0, %2, %1, %0" : "+v"(a2) : "v"(wc[i]), "s"(hs));
        }
        {
            float* pw = &partT[buf][0];
            pw[(ra << 2) + cs] = a0;
            pw[(rb << 2) + cs] = a1;
            pw[(rc << 2) + cs] = a2;
        }

        // stage the prefetched chunk late (loads had ~14 steps of flight)
        if (tc == 14 && t + 2 < N_T) {
            float4* dst = (float4*)(&gib[par ^ 1][0][0]);
            dst[tid]        = st0;
            dst[tid + 512]  = st1;
            dst[tid + 1024] = st2;
        }

        BAR();   // partials (and any staged chunk) visible

        // gate: one output per lane, all in registers
        {
            const float4 qr = *(const float4*)&partT[buf][R << 2];
            const float4 qz = *(const float4*)&partT[buf][(R + S) << 2];
            const float4 qn = *(const float4*)&partT[buf][(R + 2 * S) << 2];
            float hr = (qr.x + qr.y) + (qr.z + qr.w) + br;
            float hz = (qz.x + qz.y) + (qz.z + qz.w) + bz;
            float hn = (qn.x + qn.y) + (qn.z + qn.w) + bn;
            float r  = 1.f / (1.f + __expf(-(gr + hr)));
            float z  = 1.f / (1.f + __expf(-(gz + hz)));
            float np = gn + r * hn;
            float e  = __expf(2.f * np);
            float n  = (e - 1.f) / (e + 1.f);   // tanh
            hreg = (1.f - z) * n + z * hreg;
            unsigned hu = (unsigned)__half_as_ushort(__float2half(hreg));
            unsigned ou = (unsigned)__builtin_amdgcn_ds_swizzle((int)hu, 0x401F);
            p = hu | (ou << 16);
        }
        // no second barrier: next matvec needs only own-wave p
    }

    // publish fp32 h, then out = h @ final_w.T + final_b
    if (wv < 4 && l < 32) hfin[R] = hreg;
    BAR();
    if (tid < 3) {
        float acc = final_b[tid];
        for (int k = 0; k < S; ++k) acc += final_w[tid * S + k] * hfin[k];
        out[tid] = acc;
    }
}

// ---------------------------------------------------------------------------
extern "C" void kernel_launch(void* const* d_in, const int* in_sizes, int n_in,
                              void* d_out, int out_size, void* d_ws, size_t ws_size,
                              hipStream_t stream) {
    const float* evs     = (const float*)d_in[0];
    const float* h0      = (const float*)d_in[1];
    const float* w_ih    = (const float*)d_in[2];
    const float* w_hh    = (const float*)d_in[3];
    const float* b_ih    = (const float*)d_in[4];
    const float* b_hh    = (const float*)d_in[5];
    const float* proj_w  = (const float*)d_in[6];
    const float* proj_b  = (const float*)d_in[7];
    const float* final_w = (const float*)d_in[8];
    const float* final_b = (const float*)d_in[9];
    float* out = (float*)d_out;

    // workspace layout (floats)
    float* gi = (float*)d_ws;                  // N_T * 384
    float* Mt = gi + (size_t)N_T * S3;         // 128 * 384
    float* b2 = Mt + (size_t)S * S3;           // 384
    float* mc = b2 + S3;                       // 384
    unsigned* Whh16 = (unsigned*)(mc + S3);    // 384 * 64 packed f16 pairs

    prep_kernel<<<S3, S, 0, stream>>>(w_ih, b_ih, proj_w, proj_b, Mt, b2, mc);
    wcvt_kernel<<<S3, 64, 0, stream>>>(w_hh, Whh16);
    gi_kernel<<<N_T / TB, S3, 0, stream>>>(evs, Mt, b2, mc, gi);
    scan_kernel<<<1, THREADS, 0, stream>>>(gi, Whh16, h0, b_hh,
                                           final_w, final_b, out);
}

// Round 3
// 11222.935 us; speedup vs baseline: 1.0943x; 1.0943x over previous
//
#include <hip/hip_runtime.h>
#include <hip/hip_fp16.h>
#include <math.h>

#define N_T 16384
#define S   128
#define S3  384
#define THREADS 256          // 4 waves, 1 per SIMD
#define CHUNK 16             // gi steps staged per LDS chunk

// raw barrier: LDS-visibility only (NO vmcnt drain -> in-flight global loads
// can cross barriers freely, unlike __syncthreads()).
#define BAR() do { \
    asm volatile("s_waitcnt lgkmcnt(0)" ::: "memory"); \
    __builtin_amdgcn_s_barrier();                      \
    asm volatile("" ::: "memory");                     \
} while (0)

// ---------------------------------------------------------------------------
// Kernel 0: fold proj into w_ih (fp32). Fold b_ih fully and the r/z parts of
// b_hh (they add linearly inside the sigmoid args). The n-part of b_hh must
// NOT be folded: n = tanh(i_n + r*(Whh_n h + b_hh_n)) scales b_hh_n by r.
//   M[j][m]  = sum_{k<127} w_ih[j][k] * proj_w[k][m]        (384 x 128)
//   b2[j]    = b_ih[j] + (j<256 ? b_hh[j] : 0) + sum_k w_ih[j][k]*proj_b[k]
//   mc[j]    = w_ih[j][127]   (mask column coeff, added only at t==0)
// ---------------------------------------------------------------------------
__global__ void prep_kernel(const float* __restrict__ w_ih,
                            const float* __restrict__ b_ih,
                            const float* __restrict__ b_hh,
                            const float* __restrict__ proj_w,
                            const float* __restrict__ proj_b,
                            float* __restrict__ Mt,
                            float* __restrict__ b2,
                            float* __restrict__ mc) {
    int j = blockIdx.x;    // 0..383
    int m = threadIdx.x;   // 0..127
    float acc = 0.f;
    for (int k = 0; k < S - 1; ++k)
        acc += w_ih[j * S + k] * proj_w[k * S + m];
    Mt[m * S3 + j] = acc;
    if (m == 0) {
        float a = 0.f;
        for (int k = 0; k < S - 1; ++k) a += w_ih[j * S + k] * proj_b[k];
        b2[j] = b_ih[j] + ((j < 2 * S) ? b_hh[j] : 0.f) + a;
        mc[j] = w_ih[j * S + (S - 1)];
    }
}

// ---------------------------------------------------------------------------
// Kernel 0b: convert w_hh to packed f16 pairs, k-split pairing:
// Whh16[j*64 + m] packs (w_hh[j][m], w_hh[j][m+64]) as half2 in one uint.
// Matches the per-step in-register h pack (h[i], h[i+64]).
// ---------------------------------------------------------------------------
__global__ void wcvt_kernel(const float* __restrict__ w_hh,
                            unsigned* __restrict__ Whh16) {
    int j = blockIdx.x;    // row 0..383
    int m = threadIdx.x;   // word 0..63
    __half2 p = __floats2half2_rn(w_hh[j * S + m], w_hh[j * S + m + 64]);
    Whh16[j * 64 + m] = *(unsigned*)&p;
}

// ---------------------------------------------------------------------------
// Kernel 1: gi[t][j] = b2[j] + dot(evs[t], M[j]) + (t==0 ? mc[j] : 0)  (fp32)
// ---------------------------------------------------------------------------
#define TB 32
__global__ void gi_kernel(const float* __restrict__ evs,
                          const float* __restrict__ Mt,
                          const float* __restrict__ b2,
                          const float* __restrict__ mc,
                          float* __restrict__ gi) {
    int j  = threadIdx.x;        // 0..383
    int t0 = blockIdx.x * TB;

    float mcol[S];
#pragma unroll
    for (int k = 0; k < S; ++k) mcol[k] = Mt[k * S3 + j];

    __shared__ float ev[TB][S];
    for (int i = j; i < TB * S; i += S3)
        ev[i / S][i % S] = evs[t0 * S + i];
    __syncthreads();

    float bb  = b2[j];
    float mcj = mc[j];
    for (int tt = 0; tt < TB; ++tt) {
        int t = t0 + tt;
        float acc = bb + ((t == 0) ? mcj : 0.f);
#pragma unroll
        for (int k = 0; k < S; ++k) acc += ev[tt][k] * mcol[k];
        gi[t * S3 + j] = acc;
    }
}

// ---------------------------------------------------------------------------
// h pack word: (h16[R], h16[R+64]) for owner lanes 0..15 of each wave.
// Partner h comes from lane^32 via v_permlane32_swap (VALU pipe, builtin so
// the compiler handles permlane hazards). With identical inputs, the two
// results of a half-swap are {own-low/cross-high, cross-low/own-high} in
// either vdst/vsrc orientation, so res0^res1^own == cross in every lane.
// ---------------------------------------------------------------------------
__device__ __forceinline__ unsigned pack_h(float hreg) {
    unsigned hu = (unsigned)__half_as_ushort(__float2half(hreg));
    auto res = __builtin_amdgcn_permlane32_swap((int)hu, (int)hu, false, false);
    unsigned cross = ((unsigned)res[0]) ^ ((unsigned)res[1]) ^ hu;
    return hu | (cross << 16);
}

// ---------------------------------------------------------------------------
// Kernel 2: sequential GRU scan. 1 workgroup, 256 threads = 4 waves (1/SIMD).
//
// ONE barrier per step; h never touches LDS (permlane exchange, VALU pipe).
//   wave c = k-chunk (wave-uniform): k words [16c,16c+16) of the
//   (h[i],h[i+64]) packing; rows l+64m, m=0..5 (6 rows/lane, 96 dot2,
//   96 weight words VGPR-resident).
//   Partials -> partT[t&1], XOR-salted: dword 4*row + (c ^ ((l>>3)&3)).
//   Gate reads one aligned ds_read_b128 per gate row (4 chunk values arrive
//   permuted -> summed, order free).
//   BAR. Gate: lane owns row R = 16c + (l&15) + 64*(l>=32); lanes 16-31 /
//   48-63 duplicate (their p is never readlane'd). n-gate bias applied as
//   r*(hn+bn). New h packed via pack_h (no DS op on the serial chain).
//   gi gate operands prefetched from LDS at step top (hidden under matvec);
//   gi chunk global loads issue at tc==0, LDS-write at tc==14 (14 steps of
//   flight; raw barriers never drain vmcnt).
// ---------------------------------------------------------------------------
__global__ __attribute__((amdgpu_flat_work_group_size(THREADS, THREADS),
                          amdgpu_waves_per_eu(1, 1))) void
scan_kernel(const float* __restrict__ gi,
            const unsigned* __restrict__ Whh16,
            const float* __restrict__ h0,
            const float* __restrict__ b_hh,
            const float* __restrict__ final_w,
            const float* __restrict__ final_b,
            float* __restrict__ out) {
    const int tid = threadIdx.x;
    const int l   = tid & 63;
    const int c   = tid >> 6;        // wave = k-chunk 0..3 (wave-uniform)

    // gate row owned by this lane; lanes 16-31 / 48-63 duplicate 0-15 / 32-47
    const int R  = (c << 4) + (l & 15) + ((l & 32) << 1);
    const int cs = c ^ ((l >> 3) & 3);          // partial-write XOR salt

    // packed f16 weight pairs: row l+64m, word i = (w[r][16c+i], w[r][16c+i+64])
    unsigned w[6][16];
    {
        const unsigned* pw = Whh16 + (size_t)l * 64 + (c << 4);
#pragma unroll
        for (int m = 0; m < 6; ++m)
#pragma unroll
            for (int i = 0; i < 16; ++i)
                w[m][i] = pw[m * 4096 + i];
    }

    __shared__ __align__(16) float gib[2][CHUNK][S3];   // gi double buffer
    __shared__ __align__(16) float partT[2][S3 * 4];    // salted partials
    __shared__ float hfin[S];

    // n-gate bias (NOT folded into gi; scaled by r below)
    float bn = b_hh[2 * S + R];

    // initial h and broadcast pack
    float hreg = h0[R];
    unsigned p = pack_h(hreg);

    // prologue: stage chunk 0 (1536 float4 / 256 thr = 6 each)
    {
        const float4* src = (const float4*)gi;
        float4* dst = (float4*)(&gib[0][0][0]);
#pragma unroll
        for (int k = 0; k < 6; ++k) dst[tid + 256 * k] = src[tid + 256 * k];
    }
    BAR();

    float4 st0 = make_float4(0.f, 0.f, 0.f, 0.f);
    float4 st1 = st0, st2 = st0, st3 = st0, st4 = st0, st5 = st0;

    for (int t = 0; t < N_T; ++t) {
        const int tc  = t & (CHUNK - 1);
        const int par = (t >> 4) & 1;
        const int buf = t & 1;

        // issue next-chunk global loads at chunk start (held in regs)
        if (tc == 0 && t + CHUNK < N_T) {
            const float4* src = (const float4*)(gi + (size_t)(t + CHUNK) * S3);
            st0 = src[tid];
            st1 = src[tid + 256];
            st2 = src[tid + 512];
            st3 = src[tid + 768];
            st4 = src[tid + 1024];
            st5 = src[tid + 1280];
        }

        // prefetch this step's gi gate operands (buffer stable all chunk)
        float gr = gib[par][tc][R];
        float gz = gib[par][tc][R + S];
        float gn = gib[par][tc][R + 2 * S];

        // matvec: 16 readlane + 96 dot2, h broadcast through SGPRs
        float a0 = 0.f, a1 = 0.f, a2 = 0.f, a3 = 0.f, a4 = 0.f, a5 = 0.f;
#pragma unroll
        for (int i = 0; i < 16; ++i) {
            int hs = __builtin_amdgcn_readlane((int)p, i);
            asm("v_dot2_f32_f16 %0, %2, %1, %0" : "+v"(a0) : "v"(w[0][i]), "s"(hs));
            asm("v_dot2_f32_f16 %0, %2, %1, %0" : "+v"(a1) : "v"(w[1][i]), "s"(hs));
            asm("v_dot2_f32_f16 %0, %2, %1, %0" : "+v"(a2) : "v"(w[2][i]), "s"(hs));
            asm("v_dot2_f32_f16 %0, %2, %1, %0" : "+v"(a3) : "v"(w[3][i]), "s"(hs));
            asm("v_dot2_f32_f16 %0, %2, %1, %0" : "+v"(a4) : "v"(w[4][i]), "s"(hs));
            asm("v_dot2_f32_f16 %0, %2, %1, %0" : "+v"(a5) : "v"(w[5][i]), "s"(hs));
        }
        {
            float* pp = &partT[buf][0];
            pp[((l)       << 2) + cs] = a0;
            pp[((l + 64)  << 2) + cs] = a1;
            pp[((l + 128) << 2) + cs] = a2;
            pp[((l + 192) << 2) + cs] = a3;
            pp[((l + 256) << 2) + cs] = a4;
            pp[((l + 320) << 2) + cs] = a5;
        }

        // stage the prefetched chunk late (loads had ~14 steps of flight)
        if (tc == 14 && t + 2 < N_T) {
            float4* dst = (float4*)(&gib[par ^ 1][0][0]);
            dst[tid]        = st0;
            dst[tid + 256]  = st1;
            dst[tid + 512]  = st2;
            dst[tid + 768]  = st3;
            dst[tid + 1024] = st4;
            dst[tid + 1280] = st5;
        }

        BAR();   // partials (and any staged chunk) visible

        // gate: one output row per lane, all in registers
        {
            const float4 qr = *(const float4*)&partT[buf][R << 2];
            const float4 qz = *(const float4*)&partT[buf][(R + S) << 2];
            const float4 qn = *(const float4*)&partT[buf][(R + 2 * S) << 2];
            float hr = (qr.x + qr.y) + (qr.z + qr.w);
            float hz = (qz.x + qz.y) + (qz.z + qz.w);
            float hn = (qn.x + qn.y) + (qn.z + qn.w);
            float r  = 1.f / (1.f + __expf(-(gr + hr)));
            float z  = 1.f / (1.f + __expf(-(gz + hz)));
            float np = gn + r * (hn + bn);
            float e  = __expf(2.f * np);
            float n  = 1.f - 2.f / (e + 1.f);   // tanh
            hreg = n + z * (hreg - n);
            p = pack_h(hreg);
        }
        // no second barrier: next matvec needs only own-wave p (lanes 0..15)
    }

    // publish fp32 h (owner lanes only), then out = h @ final_w.T + final_b
    if ((l & 16) == 0) hfin[R] = hreg;
    BAR();
    if (tid < 3) {
        float acc = final_b[tid];
        for (int k = 0; k < S; ++k) acc += final_w[tid * S + k] * hfin[k];
        out[tid] = acc;
    }
}

// ---------------------------------------------------------------------------
extern "C" void kernel_launch(void* const* d_in, const int* in_sizes, int n_in,
                              void* d_out, int out_size, void* d_ws, size_t ws_size,
                              hipStream_t stream) {
    const float* evs     = (const float*)d_in[0];
    const float* h0      = (const float*)d_in[1];
    const float* w_ih    = (const float*)d_in[2];
    const float* w_hh    = (const float*)d_in[3];
    const float* b_ih    = (const float*)d_in[4];
    const float* b_hh    = (const float*)d_in[5];
    const float* proj_w  = (const float*)d_in[6];
    const float* proj_b  = (const float*)d_in[7];
    const float* final_w = (const float*)d_in[8];
    const float* final_b = (const float*)d_in[9];
    float* out = (float*)d_out;

    // workspace layout (floats)
    float* gi = (float*)d_ws;                  // N_T * 384
    float* Mt = gi + (size_t)N_T * S3;         // 128 * 384
    float* b2 = Mt + (size_t)S * S3;           // 384
    float* mc = b2 + S3;                       // 384
    unsigned* Whh16 = (unsigned*)(mc + S3);    // 384 * 64 packed f16 pairs

    prep_kernel<<<S3, S, 0, stream>>>(w_ih, b_ih, b_hh, proj_w, proj_b, Mt, b2, mc);
    wcvt_kernel<<<S3, 64, 0, stream>>>(w_hh, Whh16);
    gi_kernel<<<N_T / TB, S3, 0, stream>>>(evs, Mt, b2, mc, gi);
    scan_kernel<<<1, THREADS, 0, stream>>>(gi, Whh16, h0, b_hh,
                                           final_w, final_b, out);
}